// Round 1
// baseline (554.699 us; speedup 1.0000x reference)
//
#include <hip/hip_runtime.h>
#include <stdint.h>

#define K_TOP 1000
#define PST 0.05f
#define BLK 256

// ---- ctrl layout (unsigned words) ----
#define C_DONE0 0
#define C_DONE1 1
#define C_DONE2 2
#define C_DONE3 3
#define C_DONE4 4
#define C_DONE5 5
#define C_CNTA  6
#define C_CNTE  7
#define C_PREFIX 8
#define C_CUM    9

__device__ __forceinline__ unsigned mapU(float f) {
  unsigned b = __float_as_uint(f);
  return (b & 0x80000000u) ? ~b : (b | 0x80000000u);
}
__device__ __forceinline__ float unmapU(unsigned u) {
  unsigned b = (u & 0x80000000u) ? (u ^ 0x80000000u) : ~u;
  return __uint_as_float(b);
}

// Runs on first wave of the last-finishing block. Picks the histogram bin
// containing the K-th largest value; updates PREFIX and CUM (count strictly above).
__device__ void select_level(const unsigned* hist, unsigned* ctrl, int shift) {
  int t = threadIdx.x;
  if (t >= 64) return;
  unsigned cumIn = ctrl[C_CUM];
  unsigned need = (unsigned)K_TOP - cumIn;   // >= 1
  unsigned h0 = hist[4 * t + 0], h1 = hist[4 * t + 1];
  unsigned h2 = hist[4 * t + 2], h3 = hist[4 * t + 3];
  unsigned v = h0 + h1 + h2 + h3;            // lane-local sum
  // inclusive suffix-sum across lanes (lane l -> sum over lanes >= l)
  #pragma unroll
  for (int d = 1; d < 64; d <<= 1) {
    unsigned q = __shfl_down(v, d);
    if (t + d < 64) v += q;
  }
  unsigned sn = __shfl_down(v, 1);
  if (t == 63) sn = 0;
  if (v >= need && sn < need) {              // exactly one lane
    unsigned c = sn;                         // count in bins above this lane's range
    unsigned hh[4] = {h0, h1, h2, h3};
    int bsel = 4 * t;
    for (int b = 3; b >= 0; --b) {
      if (c + hh[b] >= need) { bsel = 4 * t + b; break; }
      c += hh[b];
    }
    ctrl[C_PREFIX] = ctrl[C_PREFIX] | (((unsigned)bsel) << shift);
    ctrl[C_CUM] = cumIn + c;                 // strictly-above count
  }
}

__device__ __forceinline__ float scalar_dim(const int* p) {
  int v = *p;
  if (v > 0 && v < (1 << 20)) return (float)v;   // int32/int64-low-word path
  return __int_as_float(v);                      // defensive: float-typed scalar
}

__global__ void __launch_bounds__(1024) k_init(unsigned* hist, unsigned* ctrl,
                                               unsigned long long* keyBuf) {
  int t = threadIdx.x;
  if (t < 1024) hist[t] = 0u;          // 4 levels x 256 bins
  if (t < 64) ctrl[t] = 0u;
  for (int e = t; e < 4096; e += 1024) keyBuf[e] = 0ull;
}

__global__ void __launch_bounds__(BLK) k_decode(
    const float* __restrict__ cls, const float* __restrict__ reg,
    const float* __restrict__ anc, const int* __restrict__ hp,
    const int* __restrict__ wp, int A, int C,
    float4* __restrict__ boxes, unsigned* __restrict__ su,
    int* __restrict__ ci, unsigned* hist0, unsigned* ctrl, int nb) {
  __shared__ unsigned lh[256];
  int t = threadIdx.x;
  lh[t] = 0u;
  __syncthreads();
  int a = blockIdx.x * BLK + t;
  if (a < A) {
    const float* row = cls + (size_t)a * C;
    float m = -3.4e38f; int mi = 0;
    int j = 0;
    for (; j + 4 <= C; j += 4) {
      float4 v = *(const float4*)(row + j);
      if (v.x > m) { m = v.x; mi = j; }
      if (v.y > m) { m = v.y; mi = j + 1; }
      if (v.z > m) { m = v.z; mi = j + 2; }
      if (v.w > m) { m = v.w; mi = j + 3; }
    }
    for (; j < C; ++j) { float v = row[j]; if (v > m) { m = v; mi = j; } }

    float4 an = ((const float4*)anc)[a];
    float4 rg = ((const float4*)reg)[a];
    float wa = an.z - an.x, ha = an.w - an.y;
    float cxa = an.x + 0.5f * wa, cya = an.y + 0.5f * ha;
    float pcx = cxa + rg.x * 0.1f * wa;      // matches ((r*0.1)*wa) assoc
    float pcy = cya + rg.y * 0.1f * ha;
    float pw = expf(rg.z * 0.2f) * wa;
    float ph = expf(rg.w * 0.2f) * ha;
    float W = scalar_dim(wp), H = scalar_dim(hp);
    float x1 = fmaxf(pcx - 0.5f * pw, 0.f);
    float y1 = fmaxf(pcy - 0.5f * ph, 0.f);
    float x2 = fminf(pcx + 0.5f * pw, W);
    float y2 = fminf(pcy + 0.5f * ph, H);
    boxes[a] = make_float4(x1, y1, x2, y2);

    float msk = (m > PST) ? m : -1.0f;       // reference's masked score
    unsigned u = mapU(msk);
    su[a] = u;
    ci[a] = mi;
    atomicAdd(&lh[u >> 24], 1u);
  }
  __syncthreads();
  if (lh[t]) atomicAdd(&hist0[t], lh[t]);
  __shared__ int last;
  __syncthreads();                            // drain hist atomics (vmcnt0 @ barrier)
  if (t == 0) {
    unsigned old = __hip_atomic_fetch_add(&ctrl[C_DONE0], 1u,
                                          __ATOMIC_ACQ_REL, __HIP_MEMORY_SCOPE_AGENT);
    last = (old == (unsigned)(nb - 1));
  }
  __syncthreads();
  if (last) select_level(hist0, ctrl, 24);
}

__global__ void __launch_bounds__(BLK) k_hist(
    const unsigned* __restrict__ su, int A, unsigned* hist,
    unsigned* ctrl, int shift, unsigned pmask, int doneIdx, int nb) {
  __shared__ unsigned lh[256];
  int t = threadIdx.x;
  lh[t] = 0u;
  __syncthreads();
  unsigned pref = ctrl[C_PREFIX];             // from previous kernel (stream-ordered)
  int a = blockIdx.x * BLK + t;
  if (a < A) {
    unsigned u = su[a];
    if ((u & pmask) == pref) atomicAdd(&lh[(u >> shift) & 255u], 1u);
  }
  __syncthreads();
  if (lh[t]) atomicAdd(&hist[t], lh[t]);
  __shared__ int last;
  __syncthreads();
  if (t == 0) {
    unsigned old = __hip_atomic_fetch_add(&ctrl[doneIdx], 1u,
                                          __ATOMIC_ACQ_REL, __HIP_MEMORY_SCOPE_AGENT);
    last = (old == (unsigned)(nb - 1));
  }
  __syncthreads();
  if (last) select_level(hist, ctrl, shift);
}

__global__ void __launch_bounds__(BLK) k_compact(
    const unsigned* __restrict__ su, int A,
    const float4* __restrict__ boxes, const int* __restrict__ ci,
    unsigned long long* __restrict__ keyBuf, float* __restrict__ candS,
    int* __restrict__ candC, float4* __restrict__ candB,
    unsigned* ctrl, int nb) {
  int t = threadIdx.x;
  int a = blockIdx.x * BLK + t;
  unsigned uT = ctrl[C_PREFIX];               // exact u of the K-th largest
  if (a < A) {
    unsigned u = su[a];
    if (u > uT) {
      unsigned p = atomicAdd(&ctrl[C_CNTA], 1u);
      if (p < 1000u) keyBuf[p] = (((unsigned long long)u) << 32) | (unsigned)(~a);
    } else if (u == uT) {
      unsigned p = atomicAdd(&ctrl[C_CNTE], 1u);
      if (p < 3072u) keyBuf[1024 + p] = (((unsigned long long)u) << 32) | (unsigned)(~a);
    }
  }
  __shared__ int last;
  __syncthreads();
  if (t == 0) {
    unsigned old = __hip_atomic_fetch_add(&ctrl[C_DONE4], 1u,
                                          __ATOMIC_ACQ_REL, __HIP_MEMORY_SCOPE_AGENT);
    last = (old == (unsigned)(nb - 1));
  }
  __syncthreads();
  if (!last) return;

  // ---- last block: bitonic sort of 4096 keys, descending (ties -> lower idx first) ----
  __shared__ unsigned long long lds[4096];    // 32 KiB
  for (int e = t; e < 4096; e += BLK) lds[e] = keyBuf[e];
  __syncthreads();
  for (int k = 2; k <= 4096; k <<= 1) {
    for (int j = k >> 1; j > 0; j >>= 1) {
      for (int e = t; e < 4096; e += BLK) {
        int ix = e ^ j;
        if (ix > e) {
          unsigned long long x = lds[e], y = lds[ix];
          bool desc = (e & k) == 0;
          if (desc ? (x < y) : (x > y)) { lds[e] = y; lds[ix] = x; }
        }
      }
      __syncthreads();
    }
  }
  for (int q = t; q < 1024; q += BLK) {
    if (q < K_TOP) {
      unsigned long long key = lds[q];
      unsigned u = (unsigned)(key >> 32);
      unsigned idx = ~(unsigned)key;
      if (idx < (unsigned)A) {
        candS[q] = unmapU(u);
        candC[q] = ci[idx];
        candB[q] = boxes[idx];
      } else {                                // pathological pad guard
        candS[q] = -1.0f; candC[q] = -1;
        candB[q] = make_float4(0.f, 0.f, 0.f, 0.f);
      }
    } else {
      candS[q] = -1.0f;                       // padding rows 1000..1023: invalid
    }
  }
}

__global__ void __launch_bounds__(BLK) k_nms(
    const float4* __restrict__ candB, const float* __restrict__ candS,
    const int* __restrict__ candC, unsigned long long* __restrict__ mask,
    unsigned* ctrl, float* __restrict__ out, int nb) {
  int t = threadIdx.x;
  int g = blockIdx.x * BLK + t;
  int i = g >> 4, w = g & 15;
  if (i < K_TOP) {
    float4 bi = candB[i];
    float areai = (bi.z - bi.x + 1.f) * (bi.w - bi.y + 1.f);
    unsigned long long bits = 0ull;
    int j0 = w << 6;
    #pragma unroll 4
    for (int b = 0; b < 64; ++b) {
      int j = j0 + b;
      if (j > i && j < K_TOP) {
        float4 bj = candB[j];
        float xx1 = fmaxf(bi.x, bj.x);
        float yy1 = fmaxf(bi.y, bj.y);
        float xx2 = fminf(bi.z, bj.z);
        float yy2 = fminf(bi.w, bj.w);
        float iw = fmaxf(xx2 - xx1 + 1.f, 0.f);
        float ih = fmaxf(yy2 - yy1 + 1.f, 0.f);
        float inter = iw * ih;
        float areaj = (bj.z - bj.x + 1.f) * (bj.w - bj.y + 1.f);
        float iou = inter / (areai + areaj - inter);
        if (iou > 0.5f) bits |= (1ull << b);
      }
    }
    mask[g] = bits;
  }
  __shared__ int last;
  __syncthreads();
  if (t == 0) {
    unsigned old = __hip_atomic_fetch_add(&ctrl[C_DONE5], 1u,
                                          __ATOMIC_ACQ_REL, __HIP_MEMORY_SCOPE_AGENT);
    last = (old == (unsigned)(nb - 1));
  }
  __syncthreads();
  if (!last) return;

  // ---- serial greedy NMS on wave 0; lanes 0..15 own 64-bit removal words ----
  __shared__ unsigned long long keepW[16];
  if (t < 64) {
    int l = t;
    unsigned long long remv = 0ull, cw = 0ull;
    if (l < 16) {
      unsigned long long vb = 0ull;
      for (int b = 0; b < 64; ++b) {
        float s = candS[(l << 6) + b];
        if (s > PST) vb |= (1ull << b);
      }
      remv = ~vb;                             // invalid candidates start "removed"
    }
    for (int i2 = 0; i2 < K_TOP; ++i2) {
      int wq = i2 >> 6;
      if ((i2 & 63) == 0) cw = __shfl(remv, wq);             // refresh current word
      unsigned long long mrow = (l < 16) ? mask[(i2 << 4) + l] : 0ull;
      unsigned long long mvw = mask[(i2 << 4) + wq];          // uniform broadcast load
      bool removed = (cw >> (i2 & 63)) & 1ull;
      if (!removed) {
        if (l < 16) remv |= mrow;             // suppress later overlapping boxes
        cw |= mvw;                            // keep broadcast copy in sync
      }
    }
    if (l < 16) keepW[l] = ~remv;
  }
  __syncthreads();
  for (int q = t; q < K_TOP; q += BLK) {
    bool kp = (keepW[q >> 6] >> (q & 63)) & 1ull;
    float sc = candS[q];
    int cc = candC[q];
    float4 bb = candB[q];
    out[q] = kp ? sc : 0.f;
    out[K_TOP + q] = kp ? (float)cc : -1.f;
    float4 ob = kp ? bb : make_float4(0.f, 0.f, 0.f, 0.f);
    *(float4*)(out + 2 * K_TOP + 4 * q) = ob;
  }
}

extern "C" void kernel_launch(void* const* d_in, const int* in_sizes, int n_in,
                              void* d_out, int out_size, void* d_ws, size_t ws_size,
                              hipStream_t stream) {
  const float* cls = (const float*)d_in[0];
  const float* reg = (const float*)d_in[1];
  const float* anc = (const float*)d_in[2];
  const int* hp = (const int*)d_in[3];
  const int* wp = (const int*)d_in[4];
  int A = in_sizes[2] / 4;
  int C = in_sizes[0] / A;

  char* ws = (char*)d_ws;
  size_t off = 0;
  auto alloc = [&](size_t bytes) -> void* {
    void* p = ws + off;
    off = (off + bytes + 255) & ~(size_t)255;
    return p;
  };
  float4* boxes = (float4*)alloc((size_t)A * 16);
  unsigned* su = (unsigned*)alloc((size_t)A * 4);
  int* ci = (int*)alloc((size_t)A * 4);
  unsigned long long* keyBuf = (unsigned long long*)alloc(4096 * 8);
  float* candS = (float*)alloc(1024 * 4);
  int* candC = (int*)alloc(1024 * 4);
  float4* candB = (float4*)alloc(1024 * 16);
  unsigned long long* mask = (unsigned long long*)alloc((size_t)K_TOP * 16 * 8);
  unsigned* hist = (unsigned*)alloc(4 * 256 * 4);
  unsigned* ctrl = (unsigned*)alloc(256 * 4);
  (void)ws_size; (void)n_in; (void)out_size;

  int nb = (A + BLK - 1) / BLK;
  int nb2 = (16 * K_TOP + BLK - 1) / BLK;

  hipLaunchKernelGGL(k_init, dim3(1), dim3(1024), 0, stream, hist, ctrl, keyBuf);
  hipLaunchKernelGGL(k_decode, dim3(nb), dim3(BLK), 0, stream,
                     cls, reg, anc, hp, wp, A, C, boxes, su, ci, hist, ctrl, nb);
  hipLaunchKernelGGL(k_hist, dim3(nb), dim3(BLK), 0, stream,
                     su, A, hist + 256, ctrl, 16, 0xFF000000u, C_DONE1, nb);
  hipLaunchKernelGGL(k_hist, dim3(nb), dim3(BLK), 0, stream,
                     su, A, hist + 512, ctrl, 8, 0xFFFF0000u, C_DONE2, nb);
  hipLaunchKernelGGL(k_hist, dim3(nb), dim3(BLK), 0, stream,
                     su, A, hist + 768, ctrl, 0, 0xFFFFFF00u, C_DONE3, nb);
  hipLaunchKernelGGL(k_compact, dim3(nb), dim3(BLK), 0, stream,
                     su, A, boxes, ci, keyBuf, candS, candC, candB, ctrl, nb);
  hipLaunchKernelGGL(k_nms, dim3(nb2), dim3(BLK), 0, stream,
                     candB, candS, candC, mask, ctrl, (float*)d_out, nb2);
}

// Round 2
// 323.913 us; speedup vs baseline: 1.7125x; 1.7125x over previous
//
#include <hip/hip_runtime.h>
#include <stdint.h>

#define K_TOP 1000
#define PST 0.05f
#define BLK 256

// ---- ctrl layout (unsigned words) ----
#define C_DONE0 0
#define C_DONE1 1
#define C_DONE2 2
#define C_DONE3 3
#define C_CNTA  6
#define C_CNTE  7
#define C_PREFIX 8
#define C_CUM    9

__device__ __forceinline__ unsigned mapU(float f) {
  unsigned b = __float_as_uint(f);
  return (b & 0x80000000u) ? ~b : (b | 0x80000000u);
}
__device__ __forceinline__ float unmapU(unsigned u) {
  unsigned b = (u & 0x80000000u) ? (u ^ 0x80000000u) : ~u;
  return __uint_as_float(b);
}

// Runs on first wave of the last-finishing block. Picks the histogram bin
// containing the K-th largest value; updates PREFIX and CUM (count strictly above).
__device__ void select_level(const unsigned* hist, unsigned* ctrl, int shift) {
  int t = threadIdx.x;
  if (t >= 64) return;
  unsigned cumIn = ctrl[C_CUM];
  unsigned need = (unsigned)K_TOP - cumIn;   // >= 1
  unsigned h0 = hist[4 * t + 0], h1 = hist[4 * t + 1];
  unsigned h2 = hist[4 * t + 2], h3 = hist[4 * t + 3];
  unsigned v = h0 + h1 + h2 + h3;            // lane-local sum
  // inclusive suffix-sum across lanes (lane l -> sum over lanes >= l)
  #pragma unroll
  for (int d = 1; d < 64; d <<= 1) {
    unsigned q = __shfl_down(v, d);
    if (t + d < 64) v += q;
  }
  unsigned sn = __shfl_down(v, 1);
  if (t == 63) sn = 0;
  if (v >= need && sn < need) {              // exactly one lane
    unsigned c = sn;                         // count in bins above this lane's range
    unsigned hh[4] = {h0, h1, h2, h3};
    int bsel = 4 * t;
    for (int b = 3; b >= 0; --b) {
      if (c + hh[b] >= need) { bsel = 4 * t + b; break; }
      c += hh[b];
    }
    ctrl[C_PREFIX] = ctrl[C_PREFIX] | (((unsigned)bsel) << shift);
    ctrl[C_CUM] = cumIn + c;                 // strictly-above count
  }
}

__device__ __forceinline__ float scalar_dim(const int* p) {
  int v = *p;
  if (v > 0 && v < (1 << 20)) return (float)v;   // int32 path
  return __int_as_float(v);                      // defensive: float-typed scalar
}

__global__ void __launch_bounds__(1024) k_init(unsigned* hist, unsigned* ctrl,
                                               unsigned long long* keyBuf,
                                               float* candS, int* candC,
                                               float4* candB) {
  int t = threadIdx.x;
  hist[t] = 0u;                        // 4 levels x 256 bins
  if (t < 64) ctrl[t] = 0u;
  for (int e = t; e < 4096; e += 1024) keyBuf[e] = 0ull;
  candS[t] = -1.0f;
  candC[t] = -1;
  candB[t] = make_float4(0.f, 0.f, 0.f, 0.f);
}

__global__ void __launch_bounds__(BLK) k_decode(
    const float* __restrict__ cls, const float* __restrict__ reg,
    const float* __restrict__ anc, const int* __restrict__ hp,
    const int* __restrict__ wp, int A, int C,
    float4* __restrict__ boxes, unsigned* __restrict__ su,
    int* __restrict__ ci, unsigned* hist0, unsigned* ctrl, int nb) {
  __shared__ unsigned lh[256];
  int t = threadIdx.x;
  lh[t] = 0u;
  __syncthreads();
  int a = blockIdx.x * BLK + t;
  if (a < A) {
    const float* row = cls + (size_t)a * C;
    float m = -3.4e38f; int mi = 0;
    int j = 0;
    for (; j + 4 <= C; j += 4) {
      float4 v = *(const float4*)(row + j);
      if (v.x > m) { m = v.x; mi = j; }
      if (v.y > m) { m = v.y; mi = j + 1; }
      if (v.z > m) { m = v.z; mi = j + 2; }
      if (v.w > m) { m = v.w; mi = j + 3; }
    }
    for (; j < C; ++j) { float v = row[j]; if (v > m) { m = v; mi = j; } }

    float4 an = ((const float4*)anc)[a];
    float4 rg = ((const float4*)reg)[a];
    float wa = an.z - an.x, ha = an.w - an.y;
    float cxa = an.x + 0.5f * wa, cya = an.y + 0.5f * ha;
    float pcx = cxa + rg.x * 0.1f * wa;
    float pcy = cya + rg.y * 0.1f * ha;
    float pw = expf(rg.z * 0.2f) * wa;
    float ph = expf(rg.w * 0.2f) * ha;
    float W = scalar_dim(wp), H = scalar_dim(hp);
    float x1 = fmaxf(pcx - 0.5f * pw, 0.f);
    float y1 = fmaxf(pcy - 0.5f * ph, 0.f);
    float x2 = fminf(pcx + 0.5f * pw, W);
    float y2 = fminf(pcy + 0.5f * ph, H);
    boxes[a] = make_float4(x1, y1, x2, y2);

    float msk = (m > PST) ? m : -1.0f;       // reference's masked score
    unsigned u = mapU(msk);
    su[a] = u;
    ci[a] = mi;
    atomicAdd(&lh[u >> 24], 1u);
  }
  __syncthreads();
  if (lh[t]) atomicAdd(&hist0[t], lh[t]);
  __shared__ int last;
  __syncthreads();
  if (t == 0) {
    unsigned old = __hip_atomic_fetch_add(&ctrl[C_DONE0], 1u,
                                          __ATOMIC_ACQ_REL, __HIP_MEMORY_SCOPE_AGENT);
    last = (old == (unsigned)(nb - 1));
  }
  __syncthreads();
  if (last) select_level(hist0, ctrl, 24);
}

__global__ void __launch_bounds__(BLK) k_hist(
    const unsigned* __restrict__ su, int A, unsigned* hist,
    unsigned* ctrl, int shift, unsigned pmask, int doneIdx, int nb) {
  __shared__ unsigned lh[256];
  int t = threadIdx.x;
  lh[t] = 0u;
  __syncthreads();
  unsigned pref = ctrl[C_PREFIX];             // from previous kernel (stream-ordered)
  int a = blockIdx.x * BLK + t;
  if (a < A) {
    unsigned u = su[a];
    if ((u & pmask) == pref) atomicAdd(&lh[(u >> shift) & 255u], 1u);
  }
  __syncthreads();
  if (lh[t]) atomicAdd(&hist[t], lh[t]);
  __shared__ int last;
  __syncthreads();
  if (t == 0) {
    unsigned old = __hip_atomic_fetch_add(&ctrl[doneIdx], 1u,
                                          __ATOMIC_ACQ_REL, __HIP_MEMORY_SCOPE_AGENT);
    last = (old == (unsigned)(nb - 1));
  }
  __syncthreads();
  if (last) select_level(hist, ctrl, shift);
}

// Parallel scatter of candidate keys. (u > uT) -> unique top slots; (u == uT) -> ties.
__global__ void __launch_bounds__(BLK) k_compact(
    const unsigned* __restrict__ su, int A,
    unsigned long long* __restrict__ keyBuf, unsigned* ctrl) {
  int a = blockIdx.x * BLK + threadIdx.x;
  if (a >= A) return;
  unsigned uT = ctrl[C_PREFIX];               // exact u of the K-th largest
  unsigned u = su[a];
  if (u > uT) {
    unsigned p = atomicAdd(&ctrl[C_CNTA], 1u);
    if (p < 1000u) keyBuf[p] = (((unsigned long long)u) << 32) | (unsigned)(~a);
  } else if (u == uT) {
    unsigned p = atomicAdd(&ctrl[C_CNTE], 1u);
    if (p < 3072u) keyBuf[1024 + p] = (((unsigned long long)u) << 32) | (unsigned)(~a);
  }
}

// Rank-by-counting: keys are distinct (index in low bits), so position =
// #{keys > mine}. Reproduces top_k's desc-value / asc-index order exactly.
__global__ void __launch_bounds__(256) k_rank(
    const unsigned long long* __restrict__ keyBuf,
    const float4* __restrict__ boxes, const int* __restrict__ ci, int A,
    float* __restrict__ candS, int* __restrict__ candC,
    float4* __restrict__ candB) {
  __shared__ unsigned long long lds[4096];    // 32 KiB
  int t = threadIdx.x;
  for (int e = t; e < 4096; e += 256) lds[e] = keyBuf[e];
  __syncthreads();
  int s = blockIdx.x * 256 + t;
  unsigned long long k0 = lds[s];
  int rank = 0;
  #pragma unroll 8
  for (int e = 0; e < 4096; ++e) rank += (lds[e] > k0) ? 1 : 0;
  if (k0 != 0ull && rank < K_TOP) {
    unsigned u = (unsigned)(k0 >> 32);
    unsigned idx = ~(unsigned)k0;
    if (idx < (unsigned)A) {
      candS[rank] = unmapU(u);
      candC[rank] = ci[idx];
      candB[rank] = boxes[idx];
    }
  }
}

// Parallel IoU bitmask: mask[i*16+w] bit b = suppress(j=w*64+b) by i (j>i).
__global__ void __launch_bounds__(BLK) k_mask(
    const float4* __restrict__ candB, const float* __restrict__ candS,
    unsigned long long* __restrict__ mask) {
  int g = blockIdx.x * BLK + threadIdx.x;
  if (g >= 16 * 1024) return;
  int i = g >> 4, w = g & 15;
  unsigned long long bits = 0ull;
  if (i < K_TOP) {
    float4 bi = candB[i];
    float areai = (bi.z - bi.x + 1.f) * (bi.w - bi.y + 1.f);
    int j0 = w << 6;
    #pragma unroll 4
    for (int b = 0; b < 64; ++b) {
      int j = j0 + b;
      if (j > i && j < K_TOP) {
        float4 bj = candB[j];
        float xx1 = fmaxf(bi.x, bj.x);
        float yy1 = fmaxf(bi.y, bj.y);
        float xx2 = fminf(bi.z, bj.z);
        float yy2 = fminf(bi.w, bj.w);
        float iw = fmaxf(xx2 - xx1 + 1.f, 0.f);
        float ih = fmaxf(yy2 - yy1 + 1.f, 0.f);
        float inter = iw * ih;
        float areaj = (bj.z - bj.x + 1.f) * (bj.w - bj.y + 1.f);
        float iou = inter / (areai + areaj - inter);
        if (iou > 0.5f) bits |= (1ull << b);
      }
    }
  }
  mask[g] = bits;
  (void)candS;
}

// Single-block serial greedy scan. Mask rows double-buffered through LDS so
// every ds_read address is compile-time; the serial chain is pure VALU.
__global__ void __launch_bounds__(256) k_scan(
    const unsigned long long* __restrict__ mask,
    const float* __restrict__ candS, const int* __restrict__ candC,
    const float4* __restrict__ candB, float* __restrict__ out) {
  __shared__ unsigned long long buf[2][1024];  // 2 x 8 KiB (64 rows x 16 words)
  __shared__ unsigned long long keepW[16];
  int t = threadIdx.x;

  // stage word-block 0 (all threads)
  for (int e = t; e < 1024; e += 256) buf[0][e] = mask[e];
  __syncthreads();

  unsigned long long remv = 0ull;
  int l = t & 63;
  if (t < 64 && l < 16) {
    unsigned long long vb = 0ull;
    for (int b = 0; b < 64; ++b) {
      float s = candS[(l << 6) + b];
      if (s > PST) vb |= (1ull << b);
    }
    remv = ~vb;                                // invalid candidates start "removed"
  }

  for (int w = 0; w < 16; ++w) {
    // threads 64..255 prefetch the next word-block into the other buffer
    if (w + 1 < 16 && t >= 64) {
      for (int e = t - 64; e < 1024; e += 192)
        buf[(w + 1) & 1][e] = mask[(w + 1) * 1024 + e];
    }
    if (t < 64) {
      unsigned long long cw = __shfl(remv, w);
      const unsigned long long* rows = buf[w & 1];
      #pragma unroll
      for (int b = 0; b < 64; ++b) {
        unsigned long long mrow = rows[b * 16 + (l & 15)];
        unsigned long long mvw  = rows[b * 16 + w];
        unsigned long long sel = ((cw >> b) & 1ull) - 1ull;  // removed? 0 : ~0
        remv |= (mrow & sel);
        cw   |= (mvw & sel);
      }
    }
    __syncthreads();
  }

  if (t < 64 && l < 16) keepW[l] = ~remv;
  __syncthreads();

  for (int q = t; q < K_TOP; q += 256) {
    bool kp = (keepW[q >> 6] >> (q & 63)) & 1ull;
    float sc = candS[q];
    int cc = candC[q];
    float4 bb = candB[q];
    out[q] = kp ? sc : 0.f;
    out[K_TOP + q] = kp ? (float)cc : -1.f;
    float4 ob = kp ? bb : make_float4(0.f, 0.f, 0.f, 0.f);
    *(float4*)(out + 2 * K_TOP + 4 * q) = ob;
  }
}

extern "C" void kernel_launch(void* const* d_in, const int* in_sizes, int n_in,
                              void* d_out, int out_size, void* d_ws, size_t ws_size,
                              hipStream_t stream) {
  const float* cls = (const float*)d_in[0];
  const float* reg = (const float*)d_in[1];
  const float* anc = (const float*)d_in[2];
  const int* hp = (const int*)d_in[3];
  const int* wp = (const int*)d_in[4];
  int A = in_sizes[2] / 4;
  int C = in_sizes[0] / A;

  char* ws = (char*)d_ws;
  size_t off = 0;
  auto alloc = [&](size_t bytes) -> void* {
    void* p = ws + off;
    off = (off + bytes + 255) & ~(size_t)255;
    return p;
  };
  float4* boxes = (float4*)alloc((size_t)A * 16);
  unsigned* su = (unsigned*)alloc((size_t)A * 4);
  int* ci = (int*)alloc((size_t)A * 4);
  unsigned long long* keyBuf = (unsigned long long*)alloc(4096 * 8);
  float* candS = (float*)alloc(1024 * 4);
  int* candC = (int*)alloc(1024 * 4);
  float4* candB = (float4*)alloc(1024 * 16);
  unsigned long long* mask = (unsigned long long*)alloc(16384 * 8);
  unsigned* hist = (unsigned*)alloc(4 * 256 * 4);
  unsigned* ctrl = (unsigned*)alloc(256 * 4);
  (void)ws_size; (void)n_in; (void)out_size;

  int nb = (A + BLK - 1) / BLK;

  hipLaunchKernelGGL(k_init, dim3(1), dim3(1024), 0, stream,
                     hist, ctrl, keyBuf, candS, candC, candB);
  hipLaunchKernelGGL(k_decode, dim3(nb), dim3(BLK), 0, stream,
                     cls, reg, anc, hp, wp, A, C, boxes, su, ci, hist, ctrl, nb);
  hipLaunchKernelGGL(k_hist, dim3(nb), dim3(BLK), 0, stream,
                     su, A, hist + 256, ctrl, 16, 0xFF000000u, C_DONE1, nb);
  hipLaunchKernelGGL(k_hist, dim3(nb), dim3(BLK), 0, stream,
                     su, A, hist + 512, ctrl, 8, 0xFFFF0000u, C_DONE2, nb);
  hipLaunchKernelGGL(k_hist, dim3(nb), dim3(BLK), 0, stream,
                     su, A, hist + 768, ctrl, 0, 0xFFFFFF00u, C_DONE3, nb);
  hipLaunchKernelGGL(k_compact, dim3(nb), dim3(BLK), 0, stream,
                     su, A, keyBuf, ctrl);
  hipLaunchKernelGGL(k_rank, dim3(16), dim3(256), 0, stream,
                     keyBuf, boxes, ci, A, candS, candC, candB);
  hipLaunchKernelGGL(k_mask, dim3(64), dim3(BLK), 0, stream,
                     candB, candS, mask);
  hipLaunchKernelGGL(k_scan, dim3(1), dim3(256), 0, stream,
                     mask, candS, candC, candB, (float*)d_out);
}